// Round 10
// baseline (123.243 us; speedup 1.0000x reference)
//
#include <hip/hip_runtime.h>
#include <hip/hip_bf16.h>

// LearnedPairConnect: B=4, N=512, D=48. Output FP32.
// out[i] = sum_j softmax_j(||P_ij||) * P_ij, P = MLP3(concat(x_i,x_j)), j<=i.
// Layer-1 linear split: U = x@W1_top + b1, V = x@W1_bot (uv_kernel).
// R10 = R7 (barrier-free wave-private K-loop, LDS A-staging, tanh-gelu)
//  + W2 B-frags demoted to per-trip ds_read_b128 (loop-invariant addresses,
//    hidden behind the gelu chain) so regs ~= 64V + 24A(W3) = 88
//  + __launch_bounds__(256,5): 5 waves/SIMD (was 4; the ~30% stall shrinks)
//  + b2/b3 folded into MFMA C-initializers (C-layout bias is col-only).
// History: R8 LDS-table gelu lost (data-dependent gathers); R9 register-direct
// A-frags lost (removed the staging decoupler); R6 spills are catastrophic —
// tripwire is WRITE_SIZE >> 384 KB.

constexpr int BATCH = 4;
constexpr int SEQ   = 512;
constexpr int DIM   = 48;
constexpr int DIM2  = 96;
constexpr int CH    = 64;

constexpr int AW  = 104;   // sA row stride (shorts): 208B rows, 16B-aligned, bank-spread
constexpr int WW  = 96;    // W2T row stride (shorts): 192B rows, 2-way banks (free)
constexpr int HW  = 72;    // sH row stride (shorts): 144B rows, 16B-aligned

constexpr int OFF_SA   = 0;            // 13312 B (A tiles; merge area after loop)
constexpr int OFF_W2T  = 13312;        //  9216 B (persistent W2^T)
constexpr int OFF_SH   = 22528;        //  9216 B (W3T staging -> H tiles)
constexpr int OFF_SUI  = 31744;        //   384 B
constexpr int LDS_SIZE = 32128;        // 5 blocks/CU: 5*32256 = 161280 <= 163840

typedef short short8v __attribute__((ext_vector_type(8)));
typedef float float4v __attribute__((ext_vector_type(4)));
typedef unsigned int uint2v __attribute__((ext_vector_type(2)));

#define MFMA16(a, b, c) __builtin_amdgcn_mfma_f32_16x16x32_bf16(a, b, c, 0, 0, 0)

// Minimal tanh-gelu: gelu(x) = x * (1 - 1/(1 + 2^(x*(c1 + c2*x^2)))).
// c1 = 2*log2(e)*sqrt(2/pi), c2 = c1*0.044715. |err vs exact gelu| <= ~1.5e-4.
__device__ __forceinline__ float gelu_tanh(float x) {
    float u = x * x;
    float q = fmaf(0.10294537f, u, 2.3022077f);
    float e = __builtin_amdgcn_exp2f(x * q);
    float r = __builtin_amdgcn_rcpf(e + 1.0f);
    return fmaf(-x, r, x);
}
__device__ __forceinline__ short f2bf1(float v) {   // bf16 round-half-up
    return (short)((__float_as_uint(v) + 0x8000u) >> 16);
}
// pack two f32 -> (bf16(b)<<16)|bf16(a); low short = a
__device__ __forceinline__ unsigned pack_bf16x2(float a, float b) {
    unsigned ua = __float_as_uint(a) + 0x8000u;
    unsigned ub = __float_as_uint(b) + 0x8000u;
    return __builtin_amdgcn_perm(ub, ua, 0x07060302u);
}
constexpr float LOG2E = 1.4426950408889634f;

// ---------------- Kernel 1: U = x@W1[:48,:] + b1 ; V = x@W1[48:,:] ----------------
__global__ __launch_bounds__(192) void uv_kernel(
    const float* __restrict__ x, const float* __restrict__ W1,
    const float* __restrict__ b1, float* __restrict__ U, float* __restrict__ V)
{
    __shared__ float sxT[DIM * 4];
    const int t = threadIdx.x;
    const int row0 = blockIdx.x * 4;
    if (t < DIM * 4) {
        int r = t / DIM, m = t - r * DIM;
        sxT[m * 4 + r] = x[(row0 + r) * DIM + m];
    }
    __syncthreads();
    const bool isU = (t < DIM2);
    const int  k   = isU ? t : (t - DIM2);
    const float* Wcol = W1 + (isU ? 0 : DIM * DIM2) + k;
    float binit = isU ? b1[k] : 0.0f;
    float a0 = binit, a1 = binit, a2 = binit, a3 = binit;
    #pragma unroll 8
    for (int m = 0; m < DIM; ++m) {
        float wv = Wcol[m * DIM2];
        const float4 xa = *(const float4*)&sxT[m * 4];
        a0 = fmaf(wv, xa.x, a0); a1 = fmaf(wv, xa.y, a1);
        a2 = fmaf(wv, xa.z, a2); a3 = fmaf(wv, xa.w, a3);
    }
    float* dst = isU ? U : V;
    dst[(row0 + 0) * DIM2 + k] = a0; dst[(row0 + 1) * DIM2 + k] = a1;
    dst[(row0 + 2) * DIM2 + k] = a2; dst[(row0 + 3) * DIM2 + k] = a3;
}

// ---- Kernel 2: MFMA pair-MLP, barrier-free, W2 from LDS, 5 waves/SIMD ----
__global__ __launch_bounds__(256, 5) void pair_kernel(
    const float* __restrict__ U, const float* __restrict__ V,
    const float* __restrict__ W2, const float* __restrict__ b2,
    const float* __restrict__ W3, const float* __restrict__ b3,
    float* __restrict__ out)
{
    __shared__ __align__(16) char smem[LDS_SIZE];
    short* sA   = (short*)(smem + OFF_SA);     // CH x AW wave-private A tiles
    short* sW2T = (short*)(smem + OFF_W2T);    // DIM x WW persistent W2^T
    short* sH   = (short*)(smem + OFF_SH);     // CH x HW (W3T staging -> H tiles)
    float* sUi  = (float*)(smem + OFF_SUI);

    const int t   = threadIdx.x;
    const int bid = blockIdx.x;
    const int b   = bid & (BATCH - 1);
    const int i   = (SEQ - 1) - (bid >> 2);    // LPT: big rows first
    const int rowbase = b * SEQ + i;

    const int lane = t & 63;
    const int w    = t >> 6;              // wave id = M-tile (rows 16w..16w+15)
    const int col  = lane & 15;
    const int quad = lane >> 4;
    const int qo   = quad * 8;
    const int m4   = w * 16 + col;        // A-frag row (wave-private)
    const int rbase = w * 16 + quad * 4;  // C-frag row base (wave-private)

    // ---- staging: W2T -> sW2T (persistent), W3T -> sH rows 0..47, zero sH k-pad ----
    for (int idx = t; idx < DIM2 * DIM; idx += 256) {       // W2 [96][48] -> sW2T[n][k]
        int k = idx / DIM, n = idx - k * DIM;
        sW2T[n * WW + k] = f2bf1(W2[idx]);
    }
    for (int idx = t; idx < DIM * DIM; idx += 256) {        // W3 [48][48] -> sH[n][k]
        int k = idx / DIM, n = idx - k * DIM;
        sH[n * HW + k] = f2bf1(W3[idx]);
    }
    for (int idx = t; idx < CH * 16; idx += 256)            // zero sH k=48..63
        sH[(idx >> 4) * HW + 48 + (idx & 15)] = 0;
    if (t < DIM2) sUi[t] = U[rowbase * DIM2 + t];
    __syncthreads();

    // ---- loop-invariant register fragments: W3 only (24 AGPR) + biases ----
    const short* w3b = sH + col * HW + qo;
    const short8v w300 = *(const short8v*)(w3b + 0);
    const short8v w301 = *(const short8v*)(w3b + 32);
    const short8v w310 = *(const short8v*)(w3b + 16*HW + 0);
    const short8v w311 = *(const short8v*)(w3b + 16*HW + 32);
    const short8v w320 = *(const short8v*)(w3b + 32*HW + 0);
    const short8v w321 = *(const short8v*)(w3b + 32*HW + 32);
    const float bb20 = b2[col], bb21 = b2[16 + col], bb22 = b2[32 + col];
    const float bb30 = b3[col], bb31 = b3[16 + col], bb32 = b3[32 + col];
    const short* w2b = sW2T + col * WW + qo;   // in-loop W2 frag base
    __syncthreads();   // W3 frags harvested; sH becomes wave-private tile space

    // A-pack geometry: 4 lanes per row; wave w's 64 lanes cover rows 16w..16w+15
    const int pr = t >> 2;             // row index
    const int pq = t & 3;

    float acc0 = 0.f, acc1 = 0.f, acc2 = 0.f;    // wave-local weighted sums
    float m_run = -1e30f, l_run = 0.0f;           // wave-private flash state

    // per-wave trip count; V row j0+pr <= 448+63 = 511 always in-bounds
    for (int j0 = 0; j0 + (w << 4) <= i; j0 += CH) {
        const int jmax = i - j0;

        // ---- A-pack: A = gelu(U_i + V_j) -> bf16 LDS, own 16 rows
        {
            const float* Vb = V + (b * SEQ + j0 + pr) * DIM2 + pq * 24;
            const float* Ub = sUi + pq * 24;
            #pragma unroll
            for (int kk = 0; kk < 3; ++kk) {
                const float4 v0 = *(const float4*)(Vb + kk * 8);
                const float4 v1 = *(const float4*)(Vb + kk * 8 + 4);
                const float4 u0 = *(const float4*)(Ub + kk * 8);
                const float4 u1 = *(const float4*)(Ub + kk * 8 + 4);
                float g0 = gelu_tanh(u0.x + v0.x);
                float g1 = gelu_tanh(u0.y + v0.y);
                float g2 = gelu_tanh(u0.z + v0.z);
                float g3 = gelu_tanh(u0.w + v0.w);
                float g4 = gelu_tanh(u1.x + v1.x);
                float g5 = gelu_tanh(u1.y + v1.y);
                float g6 = gelu_tanh(u1.z + v1.z);
                float g7 = gelu_tanh(u1.w + v1.w);
                uint2v o0, o1;
                o0.x = pack_bf16x2(g0, g1);
                o0.y = pack_bf16x2(g2, g3);
                o1.x = pack_bf16x2(g4, g5);
                o1.y = pack_bf16x2(g6, g7);
                *(uint2v*)&sA[pr * AW + pq * 24 + kk * 8]     = o0;
                *(uint2v*)&sA[pr * AW + pq * 24 + kk * 8 + 4] = o1;
            }
        }
        // no barrier: in-order DS pipe (same-wave write -> read)

        // ---- GEMM2: H = gelu(A @ W2 + b2), K=96; W2 B-frags from LDS (9x b128)
        {
            const short* arow = &sA[m4 * AW + qo];
            short8v a0 = *(const short8v*)(arow + 0);
            short8v a1 = *(const short8v*)(arow + 32);
            short8v a2 = *(const short8v*)(arow + 64);
            float4v c0 = {bb20, bb20, bb20, bb20};
            float4v c1 = {bb21, bb21, bb21, bb21};
            float4v c2 = {bb22, bb22, bb22, bb22};
            c0 = MFMA16(a0, *(const short8v*)(w2b + 0),          c0);
            c0 = MFMA16(a1, *(const short8v*)(w2b + 32),         c0);
            c0 = MFMA16(a2, *(const short8v*)(w2b + 64),         c0);
            c1 = MFMA16(a0, *(const short8v*)(w2b + 16*WW + 0),  c1);
            c1 = MFMA16(a1, *(const short8v*)(w2b + 16*WW + 32), c1);
            c1 = MFMA16(a2, *(const short8v*)(w2b + 16*WW + 64), c1);
            c2 = MFMA16(a0, *(const short8v*)(w2b + 32*WW + 0),  c2);
            c2 = MFMA16(a1, *(const short8v*)(w2b + 32*WW + 32), c2);
            c2 = MFMA16(a2, *(const short8v*)(w2b + 32*WW + 64), c2);
            #pragma unroll
            for (int r = 0; r < 4; ++r) {
                sH[(rbase + r) * HW +  0 + col] = f2bf1(gelu_tanh(c0[r]));
                sH[(rbase + r) * HW + 16 + col] = f2bf1(gelu_tanh(c1[r]));
                sH[(rbase + r) * HW + 32 + col] = f2bf1(gelu_tanh(c2[r]));
            }
        }
        // no barrier: same-wave rows only

        // ---- GEMM3 + per-wave flash update (bias pre-folded into C-init)
        {
            const short* hrw = &sH[m4 * HW + qo];
            short8v h0 = *(const short8v*)(hrw + 0);
            short8v h1 = *(const short8v*)(hrw + 32);
            float4v p0 = {bb30, bb30, bb30, bb30};
            float4v p1 = {bb31, bb31, bb31, bb31};
            float4v p2 = {bb32, bb32, bb32, bb32};
            p0 = MFMA16(h0, w300, p0); p0 = MFMA16(h1, w301, p0);
            p1 = MFMA16(h0, w310, p1); p1 = MFMA16(h1, w311, p1);
            p2 = MFMA16(h0, w320, p2); p2 = MFMA16(h1, w321, p2);
            float vr[4];
            #pragma unroll
            for (int r = 0; r < 4; ++r) {
                float ss = p0[r]*p0[r] + p1[r]*p1[r] + p2[r]*p2[r];
                ss += __shfl_xor(ss, 1);
                ss += __shfl_xor(ss, 2);
                ss += __shfl_xor(ss, 4);
                ss += __shfl_xor(ss, 8);   // full ||P_row||^2 across quad's 16 lanes
                vr[r] = (rbase + r <= jmax) ? __builtin_amdgcn_sqrtf(ss) : -1e30f;
            }
            float mloc = fmaxf(fmaxf(vr[0], vr[1]), fmaxf(vr[2], vr[3]));
            mloc = fmaxf(mloc, __shfl_xor(mloc, 16));
            mloc = fmaxf(mloc, __shfl_xor(mloc, 32));   // max over wave's 16 rows
            float newm = fmaxf(m_run, mloc);
            float sc = __builtin_amdgcn_exp2f((m_run - newm) * LOG2E);  // 0 on 1st chunk
            float e0 = __builtin_amdgcn_exp2f((vr[0] - newm) * LOG2E);  // masked -> 0
            float e1 = __builtin_amdgcn_exp2f((vr[1] - newm) * LOG2E);
            float e2 = __builtin_amdgcn_exp2f((vr[2] - newm) * LOG2E);
            float e3 = __builtin_amdgcn_exp2f((vr[3] - newm) * LOG2E);
            float s = (e0 + e1) + (e2 + e3);
            s += __shfl_xor(s, 16);
            s += __shfl_xor(s, 32);        // sum over wave's 16 rows
            l_run = fmaf(l_run, sc, s);
            m_run = newm;
            acc0 *= sc; acc1 *= sc; acc2 *= sc;
            acc0 = fmaf(e0, p0[0], acc0); acc1 = fmaf(e0, p1[0], acc1); acc2 = fmaf(e0, p2[0], acc2);
            acc0 = fmaf(e1, p0[1], acc0); acc1 = fmaf(e1, p1[1], acc1); acc2 = fmaf(e1, p2[1], acc2);
            acc0 = fmaf(e2, p0[2], acc0); acc1 = fmaf(e2, p1[2], acc1); acc2 = fmaf(e2, p2[2], acc2);
            acc0 = fmaf(e3, p0[3], acc0); acc1 = fmaf(e3, p1[3], acc1); acc2 = fmaf(e3, p2[3], acc2);
        }
    }

    // ---- cross-wave flash merge: out = sum_w f_w*acc_w / sum_w f_w*l_w ----
    acc0 += __shfl_xor(acc0, 16); acc0 += __shfl_xor(acc0, 32);
    acc1 += __shfl_xor(acc1, 16); acc1 += __shfl_xor(acc1, 32);
    acc2 += __shfl_xor(acc2, 16); acc2 += __shfl_xor(acc2, 32);
    float* red = (float*)smem;    // reuse sA region
    __syncthreads();              // all waves done with loop LDS
    if (lane < 16) {
        red[w * 64 + lane]      = acc0;
        red[w * 64 + 16 + lane] = acc1;
        red[w * 64 + 32 + lane] = acc2;
    }
    if (lane == 0) { red[w * 64 + 48] = m_run; red[w * 64 + 49] = l_run; }
    __syncthreads();
    if (t < DIM) {
        float mm0 = red[48],       mm1 = red[64 + 48];
        float mm2 = red[128 + 48], mm3 = red[192 + 48];
        float M = fmaxf(fmaxf(mm0, mm1), fmaxf(mm2, mm3));
        float f0 = __builtin_amdgcn_exp2f((mm0 - M) * LOG2E);  // m=-1e30 (no trips) -> 0
        float f1 = __builtin_amdgcn_exp2f((mm1 - M) * LOG2E);
        float f2 = __builtin_amdgcn_exp2f((mm2 - M) * LOG2E);
        float f3 = __builtin_amdgcn_exp2f((mm3 - M) * LOG2E);
        float num = f0 * red[t] + f1 * red[64 + t] + f2 * red[128 + t] + f3 * red[192 + t];
        float den = f0 * red[49] + f1 * red[64 + 49] + f2 * red[128 + 49] + f3 * red[192 + 49];
        out[rowbase * DIM + t] = num / den;
    }
}

extern "C" void kernel_launch(void* const* d_in, const int* in_sizes, int n_in,
                              void* d_out, int out_size, void* d_ws, size_t ws_size,
                              hipStream_t stream) {
    const float* x  = (const float*)d_in[0];
    const float* W1 = (const float*)d_in[1];
    const float* b1 = (const float*)d_in[2];
    const float* W2 = (const float*)d_in[3];
    const float* b2 = (const float*)d_in[4];
    const float* W3 = (const float*)d_in[5];
    const float* b3 = (const float*)d_in[6];
    float* out = (float*)d_out;

    float* U = (float*)d_ws;                       // [B*N, 96]
    float* V = U + BATCH * SEQ * DIM2;             // [B*N, 96]

    uv_kernel<<<BATCH * SEQ / 4, 192, 0, stream>>>(x, W1, b1, U, V);
    pair_kernel<<<BATCH * SEQ, 256, 0, stream>>>(U, V, W2, b2, W3, b3, out);
}

// Round 12
// 112.578 us; speedup vs baseline: 1.0947x; 1.0947x over previous
//
#include <hip/hip_runtime.h>
#include <hip/hip_bf16.h>

// LearnedPairConnect: B=4, N=512, D=48. Output FP32.
// out[i] = sum_j softmax_j(||P_ij||) * P_ij, P = MLP3(concat(x_i,x_j)), j<=i.
// Layer-1 linear split: U = x@W1_top + b1, V = x@W1_bot (uv_kernel).
// R12 = R11 with the cvt_pkrtz return-type fix (__fp16 vector, not _Float16).
// R11 design: R7 (proven best: barrier-free wave-private K-loop, tanh-gelu,
// 15 weight frags in AGPRs, launch_bounds(256,4)) + f16 MFMA datapath
// (v_cvt_pkrtz pack, 1-instr epilogue cvt) + biases folded into MFMA C-init.
// Measured lessons: (256,5) spills catastrophically (R6, R10); LDS-table gelu
// loses (R8); removing the A-staging decoupler loses (R9).

constexpr int BATCH = 4;
constexpr int SEQ   = 512;
constexpr int DIM   = 48;
constexpr int DIM2  = 96;
constexpr int CH    = 64;

constexpr int AW  = 104;   // sA row stride (halfs): 208B rows, 16B-aligned, bank-spread
constexpr int HW  = 72;    // sH row stride (halfs): 144B rows, 16B-aligned

constexpr int OFF_SA   = 0;            // 13312 B (A tiles; W2T staging; merge area)
constexpr int OFF_SH   = 13312;        //  9216 B (W3T staging -> H tiles)
constexpr int OFF_SUI  = 22528;        //   384 B
constexpr int LDS_SIZE = 22912;

typedef _Float16 half8 __attribute__((ext_vector_type(8)));
typedef __fp16   fp16x2 __attribute__((ext_vector_type(2)));   // cvt_pkrtz return type
typedef float float4v __attribute__((ext_vector_type(4)));
typedef unsigned int uint4vv __attribute__((ext_vector_type(4)));

#define MFMA16F(a, b, c) __builtin_amdgcn_mfma_f32_16x16x32_f16(a, b, c, 0, 0, 0)

// Minimal tanh-gelu: gelu(x) = x * (1 - 1/(1 + 2^(x*(c1 + c2*x^2)))).
// c1 = 2*log2(e)*sqrt(2/pi), c2 = c1*0.044715. |err vs exact gelu| <= ~1.5e-4.
__device__ __forceinline__ float gelu_tanh(float x) {
    float u = x * x;
    float q = fmaf(0.10294537f, u, 2.3022077f);
    float e = __builtin_amdgcn_exp2f(x * q);
    float r = __builtin_amdgcn_rcpf(e + 1.0f);
    return fmaf(-x, r, x);
}
constexpr float LOG2E = 1.4426950408889634f;

// ---------------- Kernel 1: U = x@W1[:48,:] + b1 ; V = x@W1[48:,:] ----------------
__global__ __launch_bounds__(192) void uv_kernel(
    const float* __restrict__ x, const float* __restrict__ W1,
    const float* __restrict__ b1, float* __restrict__ U, float* __restrict__ V)
{
    __shared__ float sxT[DIM * 4];
    const int t = threadIdx.x;
    const int row0 = blockIdx.x * 4;
    if (t < DIM * 4) {
        int r = t / DIM, m = t - r * DIM;
        sxT[m * 4 + r] = x[(row0 + r) * DIM + m];
    }
    __syncthreads();
    const bool isU = (t < DIM2);
    const int  k   = isU ? t : (t - DIM2);
    const float* Wcol = W1 + (isU ? 0 : DIM * DIM2) + k;
    float binit = isU ? b1[k] : 0.0f;
    float a0 = binit, a1 = binit, a2 = binit, a3 = binit;
    #pragma unroll 8
    for (int m = 0; m < DIM; ++m) {
        float wv = Wcol[m * DIM2];
        const float4 xa = *(const float4*)&sxT[m * 4];
        a0 = fmaf(wv, xa.x, a0); a1 = fmaf(wv, xa.y, a1);
        a2 = fmaf(wv, xa.z, a2); a3 = fmaf(wv, xa.w, a3);
    }
    float* dst = isU ? U : V;
    dst[(row0 + 0) * DIM2 + k] = a0; dst[(row0 + 1) * DIM2 + k] = a1;
    dst[(row0 + 2) * DIM2 + k] = a2; dst[(row0 + 3) * DIM2 + k] = a3;
}

// ---- Kernel 2: f16-MFMA pair-MLP, barrier-free K-loop, per-wave flash softmax ----
__global__ __launch_bounds__(256, 4) void pair_kernel(
    const float* __restrict__ U, const float* __restrict__ V,
    const float* __restrict__ W2, const float* __restrict__ b2,
    const float* __restrict__ W3, const float* __restrict__ b3,
    float* __restrict__ out)
{
    __shared__ __align__(16) char smem[LDS_SIZE];
    _Float16* sA  = (_Float16*)(smem + OFF_SA);   // CH x AW (staging: W2T; merge)
    _Float16* sH  = (_Float16*)(smem + OFF_SH);   // CH x HW (staging: W3T; k-pad 0)
    float*    sUi = (float*)(smem + OFF_SUI);

    const int t   = threadIdx.x;
    const int bid = blockIdx.x;
    const int b   = bid & (BATCH - 1);
    const int i   = (SEQ - 1) - (bid >> 2);    // LPT: big rows first
    const int rowbase = b * SEQ + i;

    const int lane = t & 63;
    const int w    = t >> 6;              // wave id = M-tile (rows 16w..16w+15)
    const int col  = lane & 15;
    const int quad = lane >> 4;
    const int qo   = quad * 8;
    const int m4   = w * 16 + col;        // A-frag row (wave-private)
    const int rbase = w * 16 + quad * 4;  // C-frag row base (wave-private)

    // ---- staging: W2T -> sA region (AW stride), W3T -> sH rows 0..47, zero k-pad ----
    for (int idx = t; idx < DIM2 * DIM; idx += 256) {       // W2 [96][48] -> sA[n][k]
        int k = idx / DIM, n = idx - k * DIM;
        sA[n * AW + k] = (_Float16)W2[idx];
    }
    for (int idx = t; idx < DIM * DIM; idx += 256) {        // W3 [48][48] -> sH[n][k]
        int k = idx / DIM, n = idx - k * DIM;
        sH[n * HW + k] = (_Float16)W3[idx];
    }
    for (int idx = t; idx < CH * 16; idx += 256)            // zero sH k=48..63
        sH[(idx >> 4) * HW + 48 + (idx & 15)] = (_Float16)0.0f;
    if (t < DIM2) sUi[t] = U[rowbase * DIM2 + t];
    __syncthreads();

    // ---- loop-invariant register fragments (B-operands) + biases ----
    const _Float16* w2b = sA + col * AW + qo;
    const half8 w200 = *(const half8*)(w2b + 0);
    const half8 w201 = *(const half8*)(w2b + 32);
    const half8 w202 = *(const half8*)(w2b + 64);
    const half8 w210 = *(const half8*)(w2b + 16*AW + 0);
    const half8 w211 = *(const half8*)(w2b + 16*AW + 32);
    const half8 w212 = *(const half8*)(w2b + 16*AW + 64);
    const half8 w220 = *(const half8*)(w2b + 32*AW + 0);
    const half8 w221 = *(const half8*)(w2b + 32*AW + 32);
    const half8 w222 = *(const half8*)(w2b + 32*AW + 64);
    const _Float16* w3b = sH + col * HW + qo;
    const half8 w300 = *(const half8*)(w3b + 0);
    const half8 w301 = *(const half8*)(w3b + 32);
    const half8 w310 = *(const half8*)(w3b + 16*HW + 0);
    const half8 w311 = *(const half8*)(w3b + 16*HW + 32);
    const half8 w320 = *(const half8*)(w3b + 32*HW + 0);
    const half8 w321 = *(const half8*)(w3b + 32*HW + 32);
    const float bb20 = b2[col], bb21 = b2[16 + col], bb22 = b2[32 + col];
    const float bb30 = b3[col], bb31 = b3[16 + col], bb32 = b3[32 + col];
    __syncthreads();   // frags harvested; sA/sH become wave-private tile space

    // A-pack geometry: 4 lanes per row; wave w's 64 lanes cover rows 16w..16w+15
    const int pr = t >> 2;             // row index
    const int pq = t & 3;              // 24-elem chunk within the 96-wide row

    float acc0 = 0.f, acc1 = 0.f, acc2 = 0.f;    // wave-local weighted sums
    float m_run = -1e30f, l_run = 0.0f;           // wave-private flash state

    // per-wave trip count; V row j0+pr <= 448+63 = 511 always in-bounds
    for (int j0 = 0; j0 + (w << 4) <= i; j0 += CH) {
        const int jmax = i - j0;

        // ---- A-pack: A = gelu(U_i + V_j) -> f16 LDS, own 16 rows, b128 writes
        {
            const float* Vb = V + (b * SEQ + j0 + pr) * DIM2 + pq * 24;
            const float* Ub = sUi + pq * 24;
            #pragma unroll
            for (int kk = 0; kk < 3; ++kk) {
                const float4 v0 = *(const float4*)(Vb + kk * 8);
                const float4 v1 = *(const float4*)(Vb + kk * 8 + 4);
                const float4 u0 = *(const float4*)(Ub + kk * 8);
                const float4 u1 = *(const float4*)(Ub + kk * 8 + 4);
                float g0 = gelu_tanh(u0.x + v0.x);
                float g1 = gelu_tanh(u0.y + v0.y);
                float g2 = gelu_tanh(u0.z + v0.z);
                float g3 = gelu_tanh(u0.w + v0.w);
                float g4 = gelu_tanh(u1.x + v1.x);
                float g5 = gelu_tanh(u1.y + v1.y);
                float g6 = gelu_tanh(u1.z + v1.z);
                float g7 = gelu_tanh(u1.w + v1.w);
                union { fp16x2 h2[4]; uint4vv u4; } o;
                o.h2[0] = __builtin_amdgcn_cvt_pkrtz(g0, g1);
                o.h2[1] = __builtin_amdgcn_cvt_pkrtz(g2, g3);
                o.h2[2] = __builtin_amdgcn_cvt_pkrtz(g4, g5);
                o.h2[3] = __builtin_amdgcn_cvt_pkrtz(g6, g7);
                *(uint4vv*)&sA[pr * AW + pq * 24 + kk * 8] = o.u4;  // 16B aligned
            }
        }
        // no barrier: in-order DS pipe (same-wave write -> read)

        // ---- GEMM2: H = gelu(A @ W2 + b2), K=96 (reg A and B frags, bias in C-init)
        {
            const _Float16* arow = &sA[m4 * AW + qo];
            half8 a0 = *(const half8*)(arow + 0);
            half8 a1 = *(const half8*)(arow + 32);
            half8 a2 = *(const half8*)(arow + 64);
            float4v c0 = {bb20, bb20, bb20, bb20};
            float4v c1 = {bb21, bb21, bb21, bb21};
            float4v c2 = {bb22, bb22, bb22, bb22};
            c0 = MFMA16F(a0, w200, c0); c0 = MFMA16F(a1, w201, c0); c0 = MFMA16F(a2, w202, c0);
            c1 = MFMA16F(a0, w210, c1); c1 = MFMA16F(a1, w211, c1); c1 = MFMA16F(a2, w212, c1);
            c2 = MFMA16F(a0, w220, c2); c2 = MFMA16F(a1, w221, c2); c2 = MFMA16F(a2, w222, c2);
            #pragma unroll
            for (int r = 0; r < 4; ++r) {
                sH[(rbase + r) * HW +  0 + col] = (_Float16)gelu_tanh(c0[r]);
                sH[(rbase + r) * HW + 16 + col] = (_Float16)gelu_tanh(c1[r]);
                sH[(rbase + r) * HW + 32 + col] = (_Float16)gelu_tanh(c2[r]);
            }
        }
        // no barrier: same-wave rows only

        // ---- GEMM3 + per-wave flash update (bias pre-folded into C-init)
        {
            const _Float16* hrw = &sH[m4 * HW + qo];
            half8 h0 = *(const half8*)(hrw + 0);
            half8 h1 = *(const half8*)(hrw + 32);
            float4v p0 = {bb30, bb30, bb30, bb30};
            float4v p1 = {bb31, bb31, bb31, bb31};
            float4v p2 = {bb32, bb32, bb32, bb32};
            p0 = MFMA16F(h0, w300, p0); p0 = MFMA16F(h1, w301, p0);
            p1 = MFMA16F(h0, w310, p1); p1 = MFMA16F(h1, w311, p1);
            p2 = MFMA16F(h0, w320, p2); p2 = MFMA16F(h1, w321, p2);
            float vr[4];
            #pragma unroll
            for (int r = 0; r < 4; ++r) {
                float ss = p0[r]*p0[r] + p1[r]*p1[r] + p2[r]*p2[r];
                ss += __shfl_xor(ss, 1);
                ss += __shfl_xor(ss, 2);
                ss += __shfl_xor(ss, 4);
                ss += __shfl_xor(ss, 8);   // full ||P_row||^2 across quad's 16 lanes
                vr[r] = (rbase + r <= jmax) ? __builtin_amdgcn_sqrtf(ss) : -1e30f;
            }
            float mloc = fmaxf(fmaxf(vr[0], vr[1]), fmaxf(vr[2], vr[3]));
            mloc = fmaxf(mloc, __shfl_xor(mloc, 16));
            mloc = fmaxf(mloc, __shfl_xor(mloc, 32));   // max over wave's 16 rows
            float newm = fmaxf(m_run, mloc);
            float sc = __builtin_amdgcn_exp2f((m_run - newm) * LOG2E);  // 0 on 1st chunk
            float e0 = __builtin_amdgcn_exp2f((vr[0] - newm) * LOG2E);  // masked -> 0
            float e1 = __builtin_amdgcn_exp2f((vr[1] - newm) * LOG2E);
            float e2 = __builtin_amdgcn_exp2f((vr[2] - newm) * LOG2E);
            float e3 = __builtin_amdgcn_exp2f((vr[3] - newm) * LOG2E);
            float s = (e0 + e1) + (e2 + e3);
            s += __shfl_xor(s, 16);
            s += __shfl_xor(s, 32);        // sum over wave's 16 rows
            l_run = fmaf(l_run, sc, s);
            m_run = newm;
            acc0 *= sc; acc1 *= sc; acc2 *= sc;
            acc0 = fmaf(e0, p0[0], acc0); acc1 = fmaf(e0, p1[0], acc1); acc2 = fmaf(e0, p2[0], acc2);
            acc0 = fmaf(e1, p0[1], acc0); acc1 = fmaf(e1, p1[1], acc1); acc2 = fmaf(e1, p2[1], acc2);
            acc0 = fmaf(e2, p0[2], acc0); acc1 = fmaf(e2, p1[2], acc1); acc2 = fmaf(e2, p2[2], acc2);
            acc0 = fmaf(e3, p0[3], acc0); acc1 = fmaf(e3, p1[3], acc1); acc2 = fmaf(e3, p2[3], acc2);
        }
    }

    // ---- cross-wave flash merge: out = sum_w f_w*acc_w / sum_w f_w*l_w ----
    acc0 += __shfl_xor(acc0, 16); acc0 += __shfl_xor(acc0, 32);
    acc1 += __shfl_xor(acc1, 16); acc1 += __shfl_xor(acc1, 32);
    acc2 += __shfl_xor(acc2, 16); acc2 += __shfl_xor(acc2, 32);
    float* red = (float*)smem;    // reuse sA region
    __syncthreads();              // all waves done with loop LDS
    if (lane < 16) {
        red[w * 64 + lane]      = acc0;
        red[w * 64 + 16 + lane] = acc1;
        red[w * 64 + 32 + lane] = acc2;
    }
    if (lane == 0) { red[w * 64 + 48] = m_run; red[w * 64 + 49] = l_run; }
    __syncthreads();
    if (t < DIM) {
        float mm0 = red[48],       mm1 = red[64 + 48];
        float mm2 = red[128 + 48], mm3 = red[192 + 48];
        float M = fmaxf(fmaxf(mm0, mm1), fmaxf(mm2, mm3));
        float f0 = __builtin_amdgcn_exp2f((mm0 - M) * LOG2E);  // m=-1e30 (no trips) -> 0
        float f1 = __builtin_amdgcn_exp2f((mm1 - M) * LOG2E);
        float f2 = __builtin_amdgcn_exp2f((mm2 - M) * LOG2E);
        float f3 = __builtin_amdgcn_exp2f((mm3 - M) * LOG2E);
        float num = f0 * red[t] + f1 * red[64 + t] + f2 * red[128 + t] + f3 * red[192 + t];
        float den = f0 * red[49] + f1 * red[64 + 49] + f2 * red[128 + 49] + f3 * red[192 + 49];
        out[rowbase * DIM + t] = num / den;
    }
}

extern "C" void kernel_launch(void* const* d_in, const int* in_sizes, int n_in,
                              void* d_out, int out_size, void* d_ws, size_t ws_size,
                              hipStream_t stream) {
    const float* x  = (const float*)d_in[0];
    const float* W1 = (const float*)d_in[1];
    const float* b1 = (const float*)d_in[2];
    const float* W2 = (const float*)d_in[3];
    const float* b2 = (const float*)d_in[4];
    const float* W3 = (const float*)d_in[5];
    const float* b3 = (const float*)d_in[6];
    float* out = (float*)d_out;

    float* U = (float*)d_ws;                       // [B*N, 96]
    float* V = U + BATCH * SEQ * DIM2;             // [B*N, 96]

    uv_kernel<<<BATCH * SEQ / 4, 192, 0, stream>>>(x, W1, b1, U, V);
    pair_kernel<<<BATCH * SEQ, 256, 0, stream>>>(U, V, W2, b2, W3, b3, out);
}